// Round 1
// baseline (877.038 us; speedup 1.0000x reference)
//
#include <hip/hip_runtime.h>

// Problem constants
#define B_   4
#define N_   2048
#define D_   2048
#define H_   16
#define KVH_ 4
#define DH_  128
#define SCALE_ 0.08838834764831845f

typedef __bf16 bf16x8 __attribute__((ext_vector_type(8)));
typedef float  f32x4  __attribute__((ext_vector_type(4)));
typedef unsigned short ushort_t;

typedef __attribute__((address_space(1))) const void* gas_cp;
typedef __attribute__((address_space(3))) void* las_p;

__device__ __forceinline__ void gload_lds16(const void* g, void* l) {
  __builtin_amdgcn_global_load_lds((gas_cp)g, (las_p)l, 16, 0, 0);
}

__device__ __forceinline__ ushort_t f2bf(float f) {
  union { float f; unsigned u; } c;
  c.f = f;
  unsigned u = c.u;
  u += 0x7fffu + ((u >> 16) & 1u);
  return (ushort_t)(u >> 16);
}

// ---------------- f32 -> bf16 elementwise ----------------
__global__ __launch_bounds__(256) void cvt_f32_bf16_k(
    const float* __restrict__ in, ushort_t* __restrict__ out, int n) {
  int i = (blockIdx.x * 256 + threadIdx.x) * 4;
  if (i >= n) return;
  float4 v = *reinterpret_cast<const float4*>(in + i);
  ushort4 o;
  o.x = f2bf(v.x); o.y = f2bf(v.y); o.z = f2bf(v.z); o.w = f2bf(v.w);
  *reinterpret_cast<ushort4*>(out + i) = o;
}

// ---------------- transpose + convert: src KxN f32 -> dst NxK bf16 ----------------
__global__ __launch_bounds__(256) void tconv_k(
    const float* __restrict__ src, ushort_t* __restrict__ dst, int K, int N) {
  __shared__ float tile[32][33];
  int n0 = blockIdx.x * 32, k0 = blockIdx.y * 32;
  int tx = threadIdx.x, ty = threadIdx.y;
#pragma unroll
  for (int i = 0; i < 32; i += 8)
    tile[ty + i][tx] = src[(size_t)(k0 + ty + i) * N + n0 + tx];
  __syncthreads();
#pragma unroll
  for (int i = 0; i < 32; i += 8)
    dst[(size_t)(n0 + ty + i) * K + k0 + tx] = f2bf(tile[tx][ty + i]);
}

// ---------------- bf16 GEMM: C = A(MxK) * Bt(NxK)^T, m97 structure + XOR swizzle ----
template <int OUTF32>
__global__ __launch_bounds__(256, 2) void gemm_bt_k(
    const ushort_t* __restrict__ A, const ushort_t* __restrict__ Bt,
    void* __restrict__ C, int M, int N, int K) {
  __shared__ ushort_t As[128 * 64];
  __shared__ ushort_t Bs[128 * 64];
  const int tid = threadIdx.x;
  const int wave = tid >> 6, lane = tid & 63;
  const int lo = lane & 15, hi = lane >> 4;
  const int wm = wave >> 1, wn = wave & 1;
  const int m0 = blockIdx.y * 128, n0 = blockIdx.x * 128;

  f32x4 acc[4][4] = {};

  const int sr = lane >> 3;   // row within 8-row staging group
  const int sc = lane & 7;    // 16B chunk within row

  const int kTiles = K >> 6;
  for (int kt = 0; kt < kTiles; ++kt) {
    const int k0 = kt << 6;
    __syncthreads();
    // stage A,B tiles: linear LDS dest, pre-swizzled global source (chunk ^ row&7)
#pragma unroll
    for (int j = 0; j < 4; ++j) {
      int r = wave * 32 + j * 8 + sr;
      int cs = sc ^ (r & 7);
      gload_lds16(A  + (size_t)(m0 + r) * K + k0 + cs * 8, As + (wave * 32 + j * 8) * 64);
      gload_lds16(Bt + (size_t)(n0 + r) * K + k0 + cs * 8, Bs + (wave * 32 + j * 8) * 64);
    }
    __syncthreads();
#pragma unroll
    for (int ks = 0; ks < 2; ++ks) {
      bf16x8 af[4], bfr[4];
#pragma unroll
      for (int mi = 0; mi < 4; ++mi) {
        int r = wm * 64 + mi * 16 + lo;
        int cs = ((ks << 2) | hi) ^ (r & 7);
        af[mi] = *reinterpret_cast<const bf16x8*>(As + r * 64 + cs * 8);
      }
#pragma unroll
      for (int ni = 0; ni < 4; ++ni) {
        int r = wn * 64 + ni * 16 + lo;
        int cs = ((ks << 2) | hi) ^ (r & 7);
        bfr[ni] = *reinterpret_cast<const bf16x8*>(Bs + r * 64 + cs * 8);
      }
#pragma unroll
      for (int mi = 0; mi < 4; ++mi)
#pragma unroll
        for (int ni = 0; ni < 4; ++ni)
          acc[mi][ni] = __builtin_amdgcn_mfma_f32_16x16x32_bf16(af[mi], bfr[ni], acc[mi][ni], 0, 0, 0);
    }
  }
  // epilogue: C/D layout col=lane&15, row=(lane>>4)*4+reg
#pragma unroll
  for (int mi = 0; mi < 4; ++mi) {
#pragma unroll
    for (int ni = 0; ni < 4; ++ni) {
#pragma unroll
      for (int r = 0; r < 4; ++r) {
        int row = m0 + wm * 64 + mi * 16 + hi * 4 + r;
        int col = n0 + wn * 64 + ni * 16 + lo;
        float v = acc[mi][ni][r];
        if (OUTF32) reinterpret_cast<float*>(C)[(size_t)row * N + col] = v;
        else        reinterpret_cast<ushort_t*>(C)[(size_t)row * N + col] = f2bf(v);
      }
    }
  }
}

// ---------------- causal GQA flash attention ----------------
// qkv: (B*N) x 3072 bf16 rows = [Q(2048) | K(512) | V(512)]
// ob : (B*N) x 2048 bf16 (merged heads)
__global__ __launch_bounds__(256, 2) void attn_k(
    const ushort_t* __restrict__ qkv, ushort_t* __restrict__ ob) {
  __shared__ ushort_t Ks[32 * 128];    // [kvrow][d], 16B chunks XOR-swizzled by row&7
  __shared__ ushort_t Vt[128 * 40];    // [d][kvrow], rows padded to 40 (80B, 16B-aligned)
  __shared__ ushort_t Pl[4][16 * 40];  // per-wave P, [qrow][kv], padded to 40

  const int nq = blockIdx.x;
  const int bh = blockIdx.y;
  const int b = bh >> 4, h = bh & 15, kvh = h & 3;   // jnp.tile => kv head = h % KVH
  const int tid = threadIdx.x, wave = tid >> 6, lane = tid & 63;
  const int lo = lane & 15, hi = lane >> 4;
  const int q0 = nq * 64 + wave * 16;

  const ushort_t* qbase = qkv + (size_t)(b * N_) * 3072;

  // Q fragments (A-operand): row = lo, k = kf*32 + hi*8 + j
  bf16x8 qf[4];
  {
    const ushort_t* qrow = qbase + (size_t)(q0 + lo) * 3072 + h * 128;
#pragma unroll
    for (int kf = 0; kf < 4; ++kf)
      qf[kf] = *reinterpret_cast<const bf16x8*>(qrow + kf * 32 + hi * 8);
  }

  float m[4] = {-3.0e38f, -3.0e38f, -3.0e38f, -3.0e38f};
  float l[4] = {0.f, 0.f, 0.f, 0.f};
  f32x4 o[8] = {};

  const int nk = (nq + 1) * 2;
  const int vd0 = (tid & 7) * 16;   // V staging: d-chunk
  const int vr  = tid >> 3;         // V staging: kv row
  const int ksr = lane >> 4;        // K staging: row within 4-row group
  const int ksc = lane & 15;        // K staging: chunk

  for (int kt = 0; kt < nk; ++kt) {
    const int k0 = kt * 32;
    __syncthreads();
    // stage K (global_load_lds, pre-swizzled source)
#pragma unroll
    for (int j = 0; j < 2; ++j) {
      int r = wave * 8 + j * 4 + ksr;
      int cs = ksc ^ (r & 7);
      gload_lds16(qbase + (size_t)(k0 + r) * 3072 + 2048 + kvh * 128 + cs * 8,
                  Ks + (wave * 8 + j * 4) * 128);
    }
    // stage V transposed (reg path)
    {
      const ushort_t* vsrc = qbase + (size_t)(k0 + vr) * 3072 + 2560 + kvh * 128 + vd0;
      uint4 a = *reinterpret_cast<const uint4*>(vsrc);
      uint4 c = *reinterpret_cast<const uint4*>(vsrc + 8);
      unsigned vv[8] = {a.x, a.y, a.z, a.w, c.x, c.y, c.z, c.w};
#pragma unroll
      for (int jj = 0; jj < 8; ++jj) {
        Vt[(vd0 + 2 * jj) * 40 + vr]     = (ushort_t)(vv[jj] & 0xffffu);
        Vt[(vd0 + 2 * jj + 1) * 40 + vr] = (ushort_t)(vv[jj] >> 16);
      }
    }
    __syncthreads();
    if (k0 < q0 + 16) {   // wave-uniform: skip fully-masked tiles
      // S = Q K^T  (16 x 32, two 16-col fragments)
      f32x4 s[2] = {};
#pragma unroll
      for (int cf = 0; cf < 2; ++cf) {
        int r = lo + 16 * cf;
#pragma unroll
        for (int kf = 0; kf < 4; ++kf) {
          int cs = ((kf << 2) | hi) ^ (r & 7);
          bf16x8 kb = *reinterpret_cast<const bf16x8*>(Ks + r * 128 + cs * 8);
          s[cf] = __builtin_amdgcn_mfma_f32_16x16x32_bf16(qf[kf], kb, s[cf], 0, 0, 0);
        }
      }
      // online softmax; lane holds rows hi*4+r, col lo(+16)
#pragma unroll
      for (int r = 0; r < 4; ++r) {
        int qrow = q0 + hi * 4 + r;
        float a0 = s[0][r] * SCALE_;
        float a1 = s[1][r] * SCALE_;
        if (k0 + lo > qrow)      a0 = -3.0e38f;
        if (k0 + lo + 16 > qrow) a1 = -3.0e38f;
        float mx = fmaxf(a0, a1);
#pragma unroll
        for (int off = 1; off < 16; off <<= 1)
          mx = fmaxf(mx, __shfl_xor(mx, off, 64));
        float mn = fmaxf(m[r], mx);
        float sf = __expf(m[r] - mn);
        m[r] = mn;
        float p0 = __expf(a0 - mn);
        float p1 = __expf(a1 - mn);
        float ps = p0 + p1;
#pragma unroll
        for (int off = 1; off < 16; off <<= 1)
          ps += __shfl_xor(ps, off, 64);
        l[r] = l[r] * sf + ps;
#pragma unroll
        for (int f = 0; f < 8; ++f) o[f][r] *= sf;
        int prow = hi * 4 + r;
        Pl[wave][prow * 40 + lo]      = f2bf(p0);
        Pl[wave][prow * 40 + lo + 16] = f2bf(p1);
      }
      // O += P V   (A-frag from Pl, B-frag from Vt: both ds_read_b128)
      bf16x8 pa = *reinterpret_cast<const bf16x8*>(&Pl[wave][lo * 40 + hi * 8]);
#pragma unroll
      for (int f = 0; f < 8; ++f) {
        bf16x8 vb = *reinterpret_cast<const bf16x8*>(Vt + (lo + 16 * f) * 40 + hi * 8);
        o[f] = __builtin_amdgcn_mfma_f32_16x16x32_bf16(pa, vb, o[f], 0, 0, 0);
      }
    }
  }
  // epilogue: normalize and store merged heads
  float inv[4];
#pragma unroll
  for (int r = 0; r < 4; ++r) inv[r] = 1.0f / l[r];
  ushort_t* obase = ob + (size_t)(b * N_ + q0) * 2048 + h * 128;
#pragma unroll
  for (int f = 0; f < 8; ++f)
#pragma unroll
    for (int r = 0; r < 4; ++r)
      obase[(size_t)(hi * 4 + r) * 2048 + lo + 16 * f] = f2bf(o[f][r] * inv[r]);
}

extern "C" void kernel_launch(void* const* d_in, const int* in_sizes, int n_in,
                              void* d_out, int out_size, void* d_ws, size_t ws_size,
                              hipStream_t stream) {
  const float* x  = (const float*)d_in[0];
  const float* Wq = (const float*)d_in[1];
  const float* Wk = (const float*)d_in[2];
  const float* Wv = (const float*)d_in[3];
  const float* Wo = (const float*)d_in[4];
  float* out = (float*)d_out;

  // ws layout (bf16 elements). ob aliases xb (xb dead after GEMM1).
  ushort_t* xb   = (ushort_t*)d_ws;          // 8192*2048  = 16,777,216
  ushort_t* w1t  = xb  + 16777216;           // 3072*2048  =  6,291,456 (Wq^T|Wk^T|Wv^T)
  ushort_t* wot  = w1t + 6291456;            // 2048*2048  =  4,194,304
  ushort_t* qkv  = wot + 4194304;            // 8192*3072  = 25,165,824
  ushort_t* obuf = xb;                       // alias

  cvt_f32_bf16_k<<<16384, 256, 0, stream>>>(x, xb, 16777216);
  dim3 tb(32, 8);
  tconv_k<<<dim3(64, 64), tb, 0, stream>>>(Wq, w1t,               2048, 2048);
  tconv_k<<<dim3(16, 64), tb, 0, stream>>>(Wk, w1t + 2048 * 2048, 2048, 512);
  tconv_k<<<dim3(16, 64), tb, 0, stream>>>(Wv, w1t + 2560 * 2048, 2048, 512);
  tconv_k<<<dim3(64, 64), tb, 0, stream>>>(Wo, wot,               2048, 2048);

  // QKV projection: (8192 x 2048) * (3072 x 2048)^T -> bf16 qkv
  gemm_bt_k<0><<<dim3(24, 64), 256, 0, stream>>>(xb, w1t, qkv, 8192, 3072, 2048);
  // causal GQA flash attention
  attn_k<<<dim3(32, 64), 256, 0, stream>>>(qkv, obuf);
  // output projection: (8192 x 2048) * (2048 x 2048)^T -> f32 out
  gemm_bt_k<1><<<dim3(16, 64), 256, 0, stream>>>(obuf, wot, out, 8192, 2048, 2048);
}